// Round 1
// baseline (5263.824 us; speedup 1.0000x reference)
//
#include <hip/hip_runtime.h>
#include <math.h>

#define N_NODES 50000
#define N_EDGES 600000
#define N_GRAPHS 512
#define HID 128
#define LAT 64
#define NL 4

__device__ __forceinline__ float gelu_exact(float x) {
    return 0.5f * x * (1.0f + erff(x * 0.70710678118654752f));
}

// ---------------------------------------------------------------------------
// Column stats (sum, sumsq) over M x 128 matrix -> stats[0..127]=sum, [128..255]=sumsq
// ---------------------------------------------------------------------------
__global__ __launch_bounds__(256) void col_stats(const float* __restrict__ X, int M,
                                                 float* __restrict__ stats) {
    __shared__ float sh[2][8][HID];
    int t = threadIdx.x;
    int tx = t & 31, ty = t >> 5;
    int r0 = blockIdx.x * 64;
    float s[4] = {0, 0, 0, 0}, q[4] = {0, 0, 0, 0};
    for (int i = 0; i < 8; ++i) {
        int r = r0 + ty + 8 * i;
        if (r < M) {
            float4 v = *(const float4*)(X + (long)r * HID + 4 * tx);
            s[0] += v.x; s[1] += v.y; s[2] += v.z; s[3] += v.w;
            q[0] += v.x * v.x; q[1] += v.y * v.y; q[2] += v.z * v.z; q[3] += v.w * v.w;
        }
    }
    for (int c = 0; c < 4; ++c) { sh[0][ty][4 * tx + c] = s[c]; sh[1][ty][4 * tx + c] = q[c]; }
    __syncthreads();
    if (ty == 0) {
        for (int c = 0; c < 4; ++c) {
            float a = 0, b = 0;
            for (int j = 0; j < 8; ++j) { a += sh[0][j][4 * tx + c]; b += sh[1][j][4 * tx + c]; }
            atomicAdd(stats + 4 * tx + c, a);
            atomicAdd(stats + HID + 4 * tx + c, b);
        }
    }
}

// scale = g * rsqrt(var + 1e-5); shift = b - mean*scale
__global__ void bn_finalize(const float* __restrict__ stats, const float* __restrict__ g,
                            const float* __restrict__ b, float invN,
                            float* __restrict__ scale, float* __restrict__ shift) {
    int c = threadIdx.x;
    float mean = stats[c] * invN;
    float var = stats[HID + c] * invN - mean * mean;
    float sc = g[c] * rsqrtf(var + 1e-5f);
    scale[c] = sc;
    shift[c] = b[c] - mean * sc;
}

// Y = maybe_gelu(X * scale[col] + shift[col]); may alias X
__global__ __launch_bounds__(256) void bn_apply(const float* __restrict__ X, float* __restrict__ Y,
                                                const float* __restrict__ scale,
                                                const float* __restrict__ shift,
                                                int M, int doGelu) {
    int i = blockIdx.x * blockDim.x + threadIdx.x;
    if (i >= M * (HID / 4)) return;
    int c4 = (i & 31) * 4;
    float4 v = ((const float4*)X)[i];
    float4 sc = *(const float4*)(scale + c4);
    float4 sf = *(const float4*)(shift + c4);
    v.x = v.x * sc.x + sf.x;
    v.y = v.y * sc.y + sf.y;
    v.z = v.z * sc.z + sf.z;
    v.w = v.w * sc.w + sf.w;
    if (doGelu) {
        v.x = gelu_exact(v.x); v.y = gelu_exact(v.y);
        v.z = gelu_exact(v.z); v.w = gelu_exact(v.w);
    }
    ((float4*)Y)[i] = v;
}

// Hp = (1 + eps[l]) * X
__global__ __launch_bounds__(256) void hpre_init(const float* __restrict__ X, float* __restrict__ Hp,
                                                 const float* __restrict__ eps, int l) {
    int i = blockIdx.x * blockDim.x + threadIdx.x;
    if (i >= N_NODES * (HID / 4)) return;
    float c = 1.0f + eps[l];
    float4 v = ((const float4*)X)[i];
    v.x *= c; v.y *= c; v.z *= c; v.w *= c;
    ((float4*)Hp)[i] = v;
}

// Hp[dst[e]] += X[src[e]]  (atomic scatter, 1 thread per (edge, 4-feature quad))
__global__ __launch_bounds__(256) void edge_scatter(const float* __restrict__ X,
                                                    float* __restrict__ Hp,
                                                    const int* __restrict__ src,
                                                    const int* __restrict__ dst) {
    long i = (long)blockIdx.x * blockDim.x + threadIdx.x;
    if (i >= (long)N_EDGES * 32) return;
    int e = (int)(i >> 5);
    int q = ((int)i & 31) * 4;
    int s = src[e], d = dst[e];
    float4 v = *(const float4*)(X + (long)s * HID + q);
    float* o = Hp + (long)d * HID + q;
    atomicAdd(o + 0, v.x);
    atomicAdd(o + 1, v.y);
    atomicAdd(o + 2, v.z);
    atomicAdd(o + 3, v.w);
}

// ---------------------------------------------------------------------------
// C[M,128] = maybe(gelu(A*scale+shift)) @ W[128,128] + bias; accumulates column
// sum/sumsq of C into stats (for the following BatchNorm).
// Block: 256 threads = 64 rows; thread (tx,ty): cols 4tx..4tx+3, rows ty+8i.
// ---------------------------------------------------------------------------
__global__ __launch_bounds__(256) void gemm128(const float* __restrict__ A,
                                               const float* __restrict__ W,
                                               const float* __restrict__ bias,
                                               float* __restrict__ C,
                                               const float* __restrict__ scale,
                                               const float* __restrict__ shift,
                                               int applyIn,
                                               float* __restrict__ stats, int M) {
    __shared__ float As[64][132];  // +4 pad: breaks stride-128 bank aliasing
    int t = threadIdx.x;
    int tx = t & 31, ty = t >> 5;
    int r0 = blockIdx.x * 64;

    // stage A tile (with optional BN+gelu transform on load)
    for (int j = 0; j < 8; ++j) {
        int idx = j * 256 + t;       // 0..2047 float4 slots
        int row = idx >> 5;
        int c4 = (idx & 31) * 4;
        float4 v = make_float4(0.f, 0.f, 0.f, 0.f);
        int r = r0 + row;
        if (r < M) v = *(const float4*)(A + (long)r * HID + c4);
        if (applyIn) {
            float4 sc = *(const float4*)(scale + c4);
            float4 sf = *(const float4*)(shift + c4);
            v.x = gelu_exact(v.x * sc.x + sf.x);
            v.y = gelu_exact(v.y * sc.y + sf.y);
            v.z = gelu_exact(v.z * sc.z + sf.z);
            v.w = gelu_exact(v.w * sc.w + sf.w);
        }
        *(float4*)(&As[row][c4]) = v;
    }
    __syncthreads();

    float acc[8][4];
#pragma unroll
    for (int i = 0; i < 8; ++i)
#pragma unroll
        for (int c = 0; c < 4; ++c) acc[i][c] = 0.f;

    for (int kq = 0; kq < 32; ++kq) {
        float4 w0 = *(const float4*)(W + (4 * kq + 0) * HID + 4 * tx);
        float4 w1 = *(const float4*)(W + (4 * kq + 1) * HID + 4 * tx);
        float4 w2 = *(const float4*)(W + (4 * kq + 2) * HID + 4 * tx);
        float4 w3 = *(const float4*)(W + (4 * kq + 3) * HID + 4 * tx);
#pragma unroll
        for (int i = 0; i < 8; ++i) {
            float4 a = *(const float4*)(&As[ty + 8 * i][4 * kq]);
            acc[i][0] += a.x * w0.x + a.y * w1.x + a.z * w2.x + a.w * w3.x;
            acc[i][1] += a.x * w0.y + a.y * w1.y + a.z * w2.y + a.w * w3.y;
            acc[i][2] += a.x * w0.z + a.y * w1.z + a.z * w2.z + a.w * w3.z;
            acc[i][3] += a.x * w0.w + a.y * w1.w + a.z * w2.w + a.w * w3.w;
        }
    }

    float4 bb = *(const float4*)(bias + 4 * tx);
    float s[4] = {0, 0, 0, 0}, q[4] = {0, 0, 0, 0};
#pragma unroll
    for (int i = 0; i < 8; ++i) {
        int r = r0 + ty + 8 * i;
        if (r < M) {
            float4 z;
            z.x = acc[i][0] + bb.x;
            z.y = acc[i][1] + bb.y;
            z.z = acc[i][2] + bb.z;
            z.w = acc[i][3] + bb.w;
            *(float4*)(C + (long)r * HID + 4 * tx) = z;
            s[0] += z.x; s[1] += z.y; s[2] += z.z; s[3] += z.w;
            q[0] += z.x * z.x; q[1] += z.y * z.y; q[2] += z.z * z.z; q[3] += z.w * z.w;
        }
    }

    if (stats) {
        __syncthreads();
        float* shs = &As[0][0];  // reuse: need 2*8*128 = 2048 floats
        for (int c = 0; c < 4; ++c) {
            shs[ty * HID + 4 * tx + c] = s[c];
            shs[1024 + ty * HID + 4 * tx + c] = q[c];
        }
        __syncthreads();
        if (ty == 0) {
            for (int c = 0; c < 4; ++c) {
                float a = 0, b = 0;
                for (int j = 0; j < 8; ++j) {
                    a += shs[j * HID + 4 * tx + c];
                    b += shs[1024 + j * HID + 4 * tx + c];
                }
                atomicAdd(stats + 4 * tx + c, a);
                atomicAdd(stats + HID + 4 * tx + c, b);
            }
        }
    }
}

// JumpingKnowledge attention: one wave (64 lanes) per node, 2 features/lane
__global__ __launch_bounds__(256) void jk_attn(const float* __restrict__ H0,
                                               const float* __restrict__ H1,
                                               const float* __restrict__ H2,
                                               const float* __restrict__ H3,
                                               const float* __restrict__ att,
                                               float* __restrict__ Y) {
    long gid = (long)blockIdx.x * blockDim.x + threadIdx.x;
    int lane = (int)(gid & 63);
    int node = (int)(gid >> 6);
    if (node >= N_NODES) return;
    const float* Hs[4] = {H0, H1, H2, H3};
    float2 h[4];
    float sc[4];
#pragma unroll
    for (int l = 0; l < 4; ++l) {
        float2 v = *(const float2*)(Hs[l] + (long)node * HID + 2 * lane);
        float2 a = *(const float2*)(att + l * HID + 2 * lane);
        h[l] = v;
        float p = v.x * a.x + v.y * a.y;
#pragma unroll
        for (int off = 32; off > 0; off >>= 1) p += __shfl_xor(p, off);
        sc[l] = p * (1.0f / HID);
    }
    float m = fmaxf(fmaxf(sc[0], sc[1]), fmaxf(sc[2], sc[3]));
    float e[4], se = 0.f;
#pragma unroll
    for (int l = 0; l < 4; ++l) { e[l] = expf(sc[l] - m); se += e[l]; }
    float inv = 1.0f / se;
    float2 o = make_float2(0.f, 0.f);
#pragma unroll
    for (int l = 0; l < 4; ++l) {
        float a = e[l] * inv;
        o.x += a * h[l].x;
        o.y += a * h[l].y;
    }
    *(float2*)(Y + (long)node * HID + 2 * lane) = o;
}

// batch is sorted: record [start,end) of each graph id
__global__ void graph_ranges(const int* __restrict__ batch, int* __restrict__ gstart,
                             int* __restrict__ gend) {
    int n = blockIdx.x * blockDim.x + threadIdx.x;
    if (n >= N_NODES) return;
    int b = batch[n];
    if (n == 0 || batch[n - 1] != b) gstart[b] = n;
    if (n == N_NODES - 1 || batch[n + 1] != b) gend[b] = n + 1;
}

// pooled = sums*pw0 + mean*pw1 + max*pw2 (pw = softmax(pool_weight))
__global__ __launch_bounds__(128) void pool_kernel(const float* __restrict__ X,
                                                   const int* __restrict__ gstart,
                                                   const int* __restrict__ gend,
                                                   const float* __restrict__ pw,
                                                   float* __restrict__ pooled) {
    int g = blockIdx.x;
    int f = threadIdx.x;
    float w0 = pw[0], w1 = pw[1], w2 = pw[2];
    float m = fmaxf(w0, fmaxf(w1, w2));
    float e0 = expf(w0 - m), e1 = expf(w1 - m), e2 = expf(w2 - m);
    float inv = 1.0f / (e0 + e1 + e2);
    e0 *= inv; e1 *= inv; e2 *= inv;
    int s = gstart[g], e = gend[g];
    float sum = 0.f, mx = -INFINITY;
    for (int n = s; n < e; ++n) {
        float v = X[(long)n * HID + f];
        sum += v;
        mx = fmaxf(mx, v);
    }
    int cnt = e - s;
    float mean = cnt > 0 ? sum / (float)cnt : 0.f;
    float mxv = cnt > 0 ? mx : 0.f;
    pooled[g * HID + f] = sum * e0 + mean * e1 + mxv * e2;
}

// head: out = gelu(LN(pooled@fcA+b))+pooled, then @fcB+b -> [G, 64]
__global__ __launch_bounds__(128) void head_kernel(const float* __restrict__ pooled,
                                                   const float* __restrict__ fcAw,
                                                   const float* __restrict__ fcAb,
                                                   const float* __restrict__ lng,
                                                   const float* __restrict__ lnb,
                                                   const float* __restrict__ fcBw,
                                                   const float* __restrict__ fcBb,
                                                   float* __restrict__ out) {
    __shared__ float p[HID], q[HID], red[HID];
    int g = blockIdx.x, j = threadIdx.x;
    p[j] = pooled[g * HID + j];
    __syncthreads();
    float acc = fcAb[j];
    for (int k = 0; k < HID; ++k) acc += p[k] * fcAw[k * HID + j];
    red[j] = acc;
    __syncthreads();
    for (int off = 64; off > 0; off >>= 1) {
        if (j < off) red[j] += red[j + off];
        __syncthreads();
    }
    float mean = red[0] * (1.0f / HID);
    __syncthreads();
    float d = acc - mean;
    red[j] = d * d;
    __syncthreads();
    for (int off = 64; off > 0; off >>= 1) {
        if (j < off) red[j] += red[j + off];
        __syncthreads();
    }
    float var = red[0] * (1.0f / HID);
    float y = d * rsqrtf(var + 1e-5f) * lng[j] + lnb[j];
    q[j] = gelu_exact(y) + p[j];
    __syncthreads();
    if (j < LAT) {
        float o = fcBb[j];
        for (int k = 0; k < HID; ++k) o += q[k] * fcBw[k * LAT + j];
        out[g * LAT + j] = o;
    }
}

extern "C" void kernel_launch(void* const* d_in, const int* in_sizes, int n_in,
                              void* d_out, int out_size, void* d_ws, size_t ws_size,
                              hipStream_t stream) {
    const float* x = (const float*)d_in[0];
    const int* ei = (const int*)d_in[1];
    const int* src = ei;
    const int* dst = ei + N_EDGES;
    const int* batch = (const int*)d_in[2];
    const float* ibn_g = (const float*)d_in[3];
    const float* ibn_b = (const float*)d_in[4];
    const float* eps = (const float*)d_in[5];
    const float* fc1w = (const float*)d_in[6];
    const float* fc1b = (const float*)d_in[7];
    const float* bn1g = (const float*)d_in[8];
    const float* bn1b = (const float*)d_in[9];
    const float* fc2w = (const float*)d_in[10];
    const float* fc2b = (const float*)d_in[11];
    const float* bng = (const float*)d_in[12];
    const float* bnb = (const float*)d_in[13];
    const float* att = (const float*)d_in[14];
    const float* pw = (const float*)d_in[15];
    const float* fcAw = (const float*)d_in[16];
    const float* fcAb = (const float*)d_in[17];
    const float* lng = (const float*)d_in[18];
    const float* lnb = (const float*)d_in[19];
    const float* fcBw = (const float*)d_in[20];
    const float* fcBb = (const float*)d_in[21];
    float* out = (float*)d_out;

    float* ws = (float*)d_ws;
    const size_t NH = (size_t)N_NODES * HID;
    float* x0 = ws;                 // normalized input; later reused as x_jk
    float* hpre = x0 + NH;
    float* z1 = hpre + NH;
    float* Hl0 = z1 + NH;
    float* Hl1 = Hl0 + NH;
    float* Hl2 = Hl1 + NH;
    float* Hl3 = Hl2 + NH;
    float* Hl[4] = {Hl0, Hl1, Hl2, Hl3};
    float* stats = Hl3 + NH;        // 256 floats
    float* bnscale = stats + 256;   // 128
    float* bnshift = bnscale + HID; // 128
    float* pooled = bnshift + HID;  // 512*128
    int* gstart = (int*)(pooled + (size_t)N_GRAPHS * HID);
    int* gend = gstart + N_GRAPHS;

    const int elemBlocks = (N_NODES * (HID / 4) + 255) / 256;   // 6250
    const int rowBlocks = (N_NODES + 63) / 64;                  // 782
    const int edgeBlocks = (int)(((long)N_EDGES * 32 + 255) / 256);  // 75000
    const float invN = 1.0f / (float)N_NODES;

    // input BatchNorm
    hipMemsetAsync(stats, 0, 256 * sizeof(float), stream);
    col_stats<<<rowBlocks, 256, 0, stream>>>(x, N_NODES, stats);
    bn_finalize<<<1, 128, 0, stream>>>(stats, ibn_g, ibn_b, invN, bnscale, bnshift);
    bn_apply<<<elemBlocks, 256, 0, stream>>>(x, x0, bnscale, bnshift, N_NODES, 0);

    const float* xin = x0;
    for (int l = 0; l < NL; ++l) {
        hpre_init<<<elemBlocks, 256, 0, stream>>>(xin, hpre, eps, l);
        edge_scatter<<<edgeBlocks, 256, 0, stream>>>(xin, hpre, src, dst);

        hipMemsetAsync(stats, 0, 256 * sizeof(float), stream);
        gemm128<<<rowBlocks, 256, 0, stream>>>(hpre, fc1w + (size_t)l * HID * HID,
                                               fc1b + l * HID, z1, nullptr, nullptr, 0,
                                               stats, N_NODES);
        bn_finalize<<<1, 128, 0, stream>>>(stats, bn1g + l * HID, bn1b + l * HID, invN,
                                           bnscale, bnshift);

        hipMemsetAsync(stats, 0, 256 * sizeof(float), stream);
        gemm128<<<rowBlocks, 256, 0, stream>>>(z1, fc2w + (size_t)l * HID * HID,
                                               fc2b + l * HID, Hl[l], bnscale, bnshift, 1,
                                               stats, N_NODES);
        bn_finalize<<<1, 128, 0, stream>>>(stats, bng + l * HID, bnb + l * HID, invN,
                                           bnscale, bnshift);
        bn_apply<<<elemBlocks, 256, 0, stream>>>(Hl[l], Hl[l], bnscale, bnshift, N_NODES, 1);
        xin = Hl[l];
    }

    // JK attention -> x0 (reused)
    jk_attn<<<(int)(((long)N_NODES * 64 + 255) / 256), 256, 0, stream>>>(
        Hl[0], Hl[1], Hl[2], Hl[3], att, x0);

    // pooling
    hipMemsetAsync(gstart, 0, 2 * N_GRAPHS * sizeof(int), stream);
    graph_ranges<<<(N_NODES + 255) / 256, 256, 0, stream>>>(batch, gstart, gend);
    pool_kernel<<<N_GRAPHS, 128, 0, stream>>>(x0, gstart, gend, pw, pooled);

    // head
    head_kernel<<<N_GRAPHS, 128, 0, stream>>>(pooled, fcAw, fcAb, lng, lnb, fcBw, fcBb, out);
}

// Round 2
// 1478.507 us; speedup vs baseline: 3.5602x; 3.5602x over previous
//
#include <hip/hip_runtime.h>
#include <math.h>

#define N_NODES 50000
#define N_EDGES 600000
#define N_GRAPHS 512
#define HID 128
#define LAT 64
#define NL 4

__device__ __forceinline__ float gelu_exact(float x) {
    return 0.5f * x * (1.0f + erff(x * 0.70710678118654752f));
}

// ---------------------------------------------------------------------------
// Column stats (sum, sumsq) over M x 128 matrix -> stats[0..127]=sum, [128..255]=sumsq
// ---------------------------------------------------------------------------
__global__ __launch_bounds__(256) void col_stats(const float* __restrict__ X, int M,
                                                 float* __restrict__ stats) {
    __shared__ float sh[2][8][HID];
    int t = threadIdx.x;
    int tx = t & 31, ty = t >> 5;
    int r0 = blockIdx.x * 64;
    float s[4] = {0, 0, 0, 0}, q[4] = {0, 0, 0, 0};
    for (int i = 0; i < 8; ++i) {
        int r = r0 + ty + 8 * i;
        if (r < M) {
            float4 v = *(const float4*)(X + (long)r * HID + 4 * tx);
            s[0] += v.x; s[1] += v.y; s[2] += v.z; s[3] += v.w;
            q[0] += v.x * v.x; q[1] += v.y * v.y; q[2] += v.z * v.z; q[3] += v.w * v.w;
        }
    }
    for (int c = 0; c < 4; ++c) { sh[0][ty][4 * tx + c] = s[c]; sh[1][ty][4 * tx + c] = q[c]; }
    __syncthreads();
    if (ty == 0) {
        for (int c = 0; c < 4; ++c) {
            float a = 0, b = 0;
            for (int j = 0; j < 8; ++j) { a += sh[0][j][4 * tx + c]; b += sh[1][j][4 * tx + c]; }
            atomicAdd(stats + 4 * tx + c, a);
            atomicAdd(stats + HID + 4 * tx + c, b);
        }
    }
}

// scale = g * rsqrt(var + 1e-5); shift = b - mean*scale
__global__ void bn_finalize(const float* __restrict__ stats, const float* __restrict__ g,
                            const float* __restrict__ b, float invN,
                            float* __restrict__ scale, float* __restrict__ shift) {
    int c = threadIdx.x;
    float mean = stats[c] * invN;
    float var = stats[HID + c] * invN - mean * mean;
    float sc = g[c] * rsqrtf(var + 1e-5f);
    scale[c] = sc;
    shift[c] = b[c] - mean * sc;
}

// Y = maybe_gelu(X * scale[col] + shift[col]); may alias X
__global__ __launch_bounds__(256) void bn_apply(const float* __restrict__ X, float* __restrict__ Y,
                                                const float* __restrict__ scale,
                                                const float* __restrict__ shift,
                                                int M, int doGelu) {
    int i = blockIdx.x * blockDim.x + threadIdx.x;
    if (i >= M * (HID / 4)) return;
    int c4 = (i & 31) * 4;
    float4 v = ((const float4*)X)[i];
    float4 sc = *(const float4*)(scale + c4);
    float4 sf = *(const float4*)(shift + c4);
    v.x = v.x * sc.x + sf.x;
    v.y = v.y * sc.y + sf.y;
    v.z = v.z * sc.z + sf.z;
    v.w = v.w * sc.w + sf.w;
    if (doGelu) {
        v.x = gelu_exact(v.x); v.y = gelu_exact(v.y);
        v.z = gelu_exact(v.z); v.w = gelu_exact(v.w);
    }
    ((float4*)Y)[i] = v;
}

// ---------------------------------------------------------------------------
// CSR build: counting sort of edges by dst
// ---------------------------------------------------------------------------
__global__ __launch_bounds__(256) void csr_count(const int* __restrict__ dst,
                                                 int* __restrict__ counts) {
    int e = blockIdx.x * blockDim.x + threadIdx.x;
    if (e >= N_EDGES) return;
    atomicAdd(counts + dst[e], 1);
}

// block-level exclusive scan (pass 1): offs gets block-local exclusive scan,
// bsum[b] = block total
__global__ __launch_bounds__(256) void scan_pass1(const int* __restrict__ counts,
                                                  int* __restrict__ offs,
                                                  int* __restrict__ bsum) {
    __shared__ int sh[256];
    int t = threadIdx.x;
    int i = blockIdx.x * 256 + t;
    int v = (i < N_NODES) ? counts[i] : 0;
    sh[t] = v;
    __syncthreads();
    for (int off = 1; off < 256; off <<= 1) {
        int a = (t >= off) ? sh[t - off] : 0;
        __syncthreads();
        sh[t] += a;
        __syncthreads();
    }
    if (i < N_NODES) offs[i] = sh[t] - v;
    if (t == 255) bsum[blockIdx.x] = sh[255];
}

// scan block sums (single block; NBLK <= 256)
__global__ __launch_bounds__(256) void scan_pass2(int* __restrict__ bsum, int nblk) {
    __shared__ int sh[256];
    int t = threadIdx.x;
    int v = (t < nblk) ? bsum[t] : 0;
    sh[t] = v;
    __syncthreads();
    for (int off = 1; off < 256; off <<= 1) {
        int a = (t >= off) ? sh[t - off] : 0;
        __syncthreads();
        sh[t] += a;
        __syncthreads();
    }
    if (t < nblk) bsum[t] = sh[t] - v;  // exclusive
}

// add block offsets; also init cursor = offs
__global__ __launch_bounds__(256) void scan_pass3(int* __restrict__ offs,
                                                  const int* __restrict__ bsum,
                                                  int* __restrict__ cursor) {
    int i = blockIdx.x * 256 + threadIdx.x;
    if (i >= N_NODES) return;
    int o = offs[i] + bsum[blockIdx.x];
    offs[i] = o;
    cursor[i] = o;
}

__global__ __launch_bounds__(256) void csr_fill(const int* __restrict__ src,
                                                const int* __restrict__ dst,
                                                int* __restrict__ cursor,
                                                int* __restrict__ csr) {
    int e = blockIdx.x * blockDim.x + threadIdx.x;
    if (e >= N_EDGES) return;
    int pos = atomicAdd(cursor + dst[e], 1);
    csr[pos] = src[e];
}

// ---------------------------------------------------------------------------
// GIN aggregation (gather form): Hp[n] = (1+eps[l])*X[n] + sum_{s in in(n)} X[s]
// 32 threads per node (float4 per thread); 8 nodes per 256-block.
// ---------------------------------------------------------------------------
__global__ __launch_bounds__(256) void gin_gather(const float* __restrict__ X,
                                                  float* __restrict__ Hp,
                                                  const int* __restrict__ offs,
                                                  const int* __restrict__ counts,
                                                  const int* __restrict__ csr,
                                                  const float* __restrict__ eps, int l) {
    int t = threadIdx.x;
    int tx = t & 31;
    int node = blockIdx.x * 8 + (t >> 5);
    if (node >= N_NODES) return;
    float ev = 1.0f + eps[l];
    float4 acc = *(const float4*)(X + (long)node * HID + 4 * tx);
    acc.x *= ev; acc.y *= ev; acc.z *= ev; acc.w *= ev;
    int o = offs[node];
    int d = counts[node];
    for (int k = 0; k < d; ++k) {
        int s = csr[o + k];  // same address across the node's 32 lanes -> broadcast
        float4 v = *(const float4*)(X + (long)s * HID + 4 * tx);
        acc.x += v.x; acc.y += v.y; acc.z += v.z; acc.w += v.w;
    }
    *(float4*)(Hp + (long)node * HID + 4 * tx) = acc;
}

// ---------------------------------------------------------------------------
// C[M,128] = maybe(gelu(A*scale+shift)) @ W[128,128] + bias; accumulates column
// sum/sumsq of C into stats (for the following BatchNorm).
// ---------------------------------------------------------------------------
__global__ __launch_bounds__(256) void gemm128(const float* __restrict__ A,
                                               const float* __restrict__ W,
                                               const float* __restrict__ bias,
                                               float* __restrict__ C,
                                               const float* __restrict__ scale,
                                               const float* __restrict__ shift,
                                               int applyIn,
                                               float* __restrict__ stats, int M) {
    __shared__ float As[64][132];  // +4 pad: breaks stride-128 bank aliasing
    int t = threadIdx.x;
    int tx = t & 31, ty = t >> 5;
    int r0 = blockIdx.x * 64;

    // stage A tile (with optional BN+gelu transform on load)
    for (int j = 0; j < 8; ++j) {
        int idx = j * 256 + t;       // 0..2047 float4 slots
        int row = idx >> 5;
        int c4 = (idx & 31) * 4;
        float4 v = make_float4(0.f, 0.f, 0.f, 0.f);
        int r = r0 + row;
        if (r < M) v = *(const float4*)(A + (long)r * HID + c4);
        if (applyIn) {
            float4 sc = *(const float4*)(scale + c4);
            float4 sf = *(const float4*)(shift + c4);
            v.x = gelu_exact(v.x * sc.x + sf.x);
            v.y = gelu_exact(v.y * sc.y + sf.y);
            v.z = gelu_exact(v.z * sc.z + sf.z);
            v.w = gelu_exact(v.w * sc.w + sf.w);
        }
        *(float4*)(&As[row][c4]) = v;
    }
    __syncthreads();

    float acc[8][4];
#pragma unroll
    for (int i = 0; i < 8; ++i)
#pragma unroll
        for (int c = 0; c < 4; ++c) acc[i][c] = 0.f;

    for (int kq = 0; kq < 32; ++kq) {
        float4 w0 = *(const float4*)(W + (4 * kq + 0) * HID + 4 * tx);
        float4 w1 = *(const float4*)(W + (4 * kq + 1) * HID + 4 * tx);
        float4 w2 = *(const float4*)(W + (4 * kq + 2) * HID + 4 * tx);
        float4 w3 = *(const float4*)(W + (4 * kq + 3) * HID + 4 * tx);
#pragma unroll
        for (int i = 0; i < 8; ++i) {
            float4 a = *(const float4*)(&As[ty + 8 * i][4 * kq]);
            acc[i][0] += a.x * w0.x + a.y * w1.x + a.z * w2.x + a.w * w3.x;
            acc[i][1] += a.x * w0.y + a.y * w1.y + a.z * w2.y + a.w * w3.y;
            acc[i][2] += a.x * w0.z + a.y * w1.z + a.z * w2.z + a.w * w3.z;
            acc[i][3] += a.x * w0.w + a.y * w1.w + a.z * w2.w + a.w * w3.w;
        }
    }

    float4 bb = *(const float4*)(bias + 4 * tx);
    float s[4] = {0, 0, 0, 0}, q[4] = {0, 0, 0, 0};
#pragma unroll
    for (int i = 0; i < 8; ++i) {
        int r = r0 + ty + 8 * i;
        if (r < M) {
            float4 z;
            z.x = acc[i][0] + bb.x;
            z.y = acc[i][1] + bb.y;
            z.z = acc[i][2] + bb.z;
            z.w = acc[i][3] + bb.w;
            *(float4*)(C + (long)r * HID + 4 * tx) = z;
            s[0] += z.x; s[1] += z.y; s[2] += z.z; s[3] += z.w;
            q[0] += z.x * z.x; q[1] += z.y * z.y; q[2] += z.z * z.z; q[3] += z.w * z.w;
        }
    }

    if (stats) {
        __syncthreads();
        float* shs = &As[0][0];  // reuse: need 2*8*128 = 2048 floats
        for (int c = 0; c < 4; ++c) {
            shs[ty * HID + 4 * tx + c] = s[c];
            shs[1024 + ty * HID + 4 * tx + c] = q[c];
        }
        __syncthreads();
        if (ty == 0) {
            for (int c = 0; c < 4; ++c) {
                float a = 0, b = 0;
                for (int j = 0; j < 8; ++j) {
                    a += shs[j * HID + 4 * tx + c];
                    b += shs[1024 + j * HID + 4 * tx + c];
                }
                atomicAdd(stats + 4 * tx + c, a);
                atomicAdd(stats + HID + 4 * tx + c, b);
            }
        }
    }
}

// JumpingKnowledge attention: one wave (64 lanes) per node, 2 features/lane
__global__ __launch_bounds__(256) void jk_attn(const float* __restrict__ H0,
                                               const float* __restrict__ H1,
                                               const float* __restrict__ H2,
                                               const float* __restrict__ H3,
                                               const float* __restrict__ att,
                                               float* __restrict__ Y) {
    long gid = (long)blockIdx.x * blockDim.x + threadIdx.x;
    int lane = (int)(gid & 63);
    int node = (int)(gid >> 6);
    if (node >= N_NODES) return;
    const float* Hs[4] = {H0, H1, H2, H3};
    float2 h[4];
    float sc[4];
#pragma unroll
    for (int l = 0; l < 4; ++l) {
        float2 v = *(const float2*)(Hs[l] + (long)node * HID + 2 * lane);
        float2 a = *(const float2*)(att + l * HID + 2 * lane);
        h[l] = v;
        float p = v.x * a.x + v.y * a.y;
#pragma unroll
        for (int off = 32; off > 0; off >>= 1) p += __shfl_xor(p, off);
        sc[l] = p * (1.0f / HID);
    }
    float m = fmaxf(fmaxf(sc[0], sc[1]), fmaxf(sc[2], sc[3]));
    float e[4], se = 0.f;
#pragma unroll
    for (int l = 0; l < 4; ++l) { e[l] = expf(sc[l] - m); se += e[l]; }
    float inv = 1.0f / se;
    float2 o = make_float2(0.f, 0.f);
#pragma unroll
    for (int l = 0; l < 4; ++l) {
        float a = e[l] * inv;
        o.x += a * h[l].x;
        o.y += a * h[l].y;
    }
    *(float2*)(Y + (long)node * HID + 2 * lane) = o;
}

// batch is sorted: record [start,end) of each graph id
__global__ void graph_ranges(const int* __restrict__ batch, int* __restrict__ gstart,
                             int* __restrict__ gend) {
    int n = blockIdx.x * blockDim.x + threadIdx.x;
    if (n >= N_NODES) return;
    int b = batch[n];
    if (n == 0 || batch[n - 1] != b) gstart[b] = n;
    if (n == N_NODES - 1 || batch[n + 1] != b) gend[b] = n + 1;
}

// pooled = sums*pw0 + mean*pw1 + max*pw2 (pw = softmax(pool_weight))
__global__ __launch_bounds__(128) void pool_kernel(const float* __restrict__ X,
                                                   const int* __restrict__ gstart,
                                                   const int* __restrict__ gend,
                                                   const float* __restrict__ pw,
                                                   float* __restrict__ pooled) {
    int g = blockIdx.x;
    int f = threadIdx.x;
    float w0 = pw[0], w1 = pw[1], w2 = pw[2];
    float m = fmaxf(w0, fmaxf(w1, w2));
    float e0 = expf(w0 - m), e1 = expf(w1 - m), e2 = expf(w2 - m);
    float inv = 1.0f / (e0 + e1 + e2);
    e0 *= inv; e1 *= inv; e2 *= inv;
    int s = gstart[g], e = gend[g];
    float sum = 0.f, mx = -INFINITY;
    for (int n = s; n < e; ++n) {
        float v = X[(long)n * HID + f];
        sum += v;
        mx = fmaxf(mx, v);
    }
    int cnt = e - s;
    float mean = cnt > 0 ? sum / (float)cnt : 0.f;
    float mxv = cnt > 0 ? mx : 0.f;
    pooled[g * HID + f] = sum * e0 + mean * e1 + mxv * e2;
}

// head: out = gelu(LN(pooled@fcA+b))+pooled, then @fcB+b -> [G, 64]
__global__ __launch_bounds__(128) void head_kernel(const float* __restrict__ pooled,
                                                   const float* __restrict__ fcAw,
                                                   const float* __restrict__ fcAb,
                                                   const float* __restrict__ lng,
                                                   const float* __restrict__ lnb,
                                                   const float* __restrict__ fcBw,
                                                   const float* __restrict__ fcBb,
                                                   float* __restrict__ out) {
    __shared__ float p[HID], q[HID], red[HID];
    int g = blockIdx.x, j = threadIdx.x;
    p[j] = pooled[g * HID + j];
    __syncthreads();
    float acc = fcAb[j];
    for (int k = 0; k < HID; ++k) acc += p[k] * fcAw[k * HID + j];
    red[j] = acc;
    __syncthreads();
    for (int off = 64; off > 0; off >>= 1) {
        if (j < off) red[j] += red[j + off];
        __syncthreads();
    }
    float mean = red[0] * (1.0f / HID);
    __syncthreads();
    float d = acc - mean;
    red[j] = d * d;
    __syncthreads();
    for (int off = 64; off > 0; off >>= 1) {
        if (j < off) red[j] += red[j + off];
        __syncthreads();
    }
    float var = red[0] * (1.0f / HID);
    float y = d * rsqrtf(var + 1e-5f) * lng[j] + lnb[j];
    q[j] = gelu_exact(y) + p[j];
    __syncthreads();
    if (j < LAT) {
        float o = fcBb[j];
        for (int k = 0; k < HID; ++k) o += q[k] * fcBw[k * LAT + j];
        out[g * LAT + j] = o;
    }
}

extern "C" void kernel_launch(void* const* d_in, const int* in_sizes, int n_in,
                              void* d_out, int out_size, void* d_ws, size_t ws_size,
                              hipStream_t stream) {
    const float* x = (const float*)d_in[0];
    const int* ei = (const int*)d_in[1];
    const int* src = ei;
    const int* dst = ei + N_EDGES;
    const int* batch = (const int*)d_in[2];
    const float* ibn_g = (const float*)d_in[3];
    const float* ibn_b = (const float*)d_in[4];
    const float* eps = (const float*)d_in[5];
    const float* fc1w = (const float*)d_in[6];
    const float* fc1b = (const float*)d_in[7];
    const float* bn1g = (const float*)d_in[8];
    const float* bn1b = (const float*)d_in[9];
    const float* fc2w = (const float*)d_in[10];
    const float* fc2b = (const float*)d_in[11];
    const float* bng = (const float*)d_in[12];
    const float* bnb = (const float*)d_in[13];
    const float* att = (const float*)d_in[14];
    const float* pw = (const float*)d_in[15];
    const float* fcAw = (const float*)d_in[16];
    const float* fcAb = (const float*)d_in[17];
    const float* lng = (const float*)d_in[18];
    const float* lnb = (const float*)d_in[19];
    const float* fcBw = (const float*)d_in[20];
    const float* fcBb = (const float*)d_in[21];
    float* out = (float*)d_out;

    float* ws = (float*)d_ws;
    const size_t NH = (size_t)N_NODES * HID;
    float* x0 = ws;                 // normalized input; later reused as x_jk
    float* hpre = x0 + NH;
    float* z1 = hpre + NH;
    float* Hl0 = z1 + NH;
    float* Hl1 = Hl0 + NH;
    float* Hl2 = Hl1 + NH;
    float* Hl3 = Hl2 + NH;
    float* Hl[4] = {Hl0, Hl1, Hl2, Hl3};
    float* stats = Hl3 + NH;        // 256 floats
    float* bnscale = stats + 256;   // 128
    float* bnshift = bnscale + HID; // 128
    float* pooled = bnshift + HID;  // 512*128
    int* gstart = (int*)(pooled + (size_t)N_GRAPHS * HID);
    int* gend = gstart + N_GRAPHS;
    // CSR scratch (ints)
    int* counts = gend + N_GRAPHS;
    int* offs = counts + N_NODES;
    int* cursor = offs + N_NODES;
    int* bsum = cursor + N_NODES;        // 256
    int* csr = bsum + 256;               // N_EDGES

    const int elemBlocks = (N_NODES * (HID / 4) + 255) / 256;   // 6250
    const int rowBlocks = (N_NODES + 63) / 64;                  // 782
    const int nodeBlocks = (N_NODES + 255) / 256;               // 196
    const int edgeBlocks = (N_EDGES + 255) / 256;               // 2344
    const float invN = 1.0f / (float)N_NODES;

    // ---- CSR build (counting sort by dst) ----
    hipMemsetAsync(counts, 0, N_NODES * sizeof(int), stream);
    csr_count<<<edgeBlocks, 256, 0, stream>>>(dst, counts);
    scan_pass1<<<nodeBlocks, 256, 0, stream>>>(counts, offs, bsum);
    scan_pass2<<<1, 256, 0, stream>>>(bsum, nodeBlocks);
    scan_pass3<<<nodeBlocks, 256, 0, stream>>>(offs, bsum, cursor);
    csr_fill<<<edgeBlocks, 256, 0, stream>>>(src, dst, cursor, csr);

    // ---- input BatchNorm ----
    hipMemsetAsync(stats, 0, 256 * sizeof(float), stream);
    col_stats<<<rowBlocks, 256, 0, stream>>>(x, N_NODES, stats);
    bn_finalize<<<1, 128, 0, stream>>>(stats, ibn_g, ibn_b, invN, bnscale, bnshift);
    bn_apply<<<elemBlocks, 256, 0, stream>>>(x, x0, bnscale, bnshift, N_NODES, 0);

    const float* xin = x0;
    for (int l = 0; l < NL; ++l) {
        // fused (1+eps)*x + neighbor-sum via CSR gather (no atomics)
        gin_gather<<<(N_NODES + 7) / 8, 256, 0, stream>>>(xin, hpre, offs, counts, csr,
                                                          eps, l);

        hipMemsetAsync(stats, 0, 256 * sizeof(float), stream);
        gemm128<<<rowBlocks, 256, 0, stream>>>(hpre, fc1w + (size_t)l * HID * HID,
                                               fc1b + l * HID, z1, nullptr, nullptr, 0,
                                               stats, N_NODES);
        bn_finalize<<<1, 128, 0, stream>>>(stats, bn1g + l * HID, bn1b + l * HID, invN,
                                           bnscale, bnshift);

        hipMemsetAsync(stats, 0, 256 * sizeof(float), stream);
        gemm128<<<rowBlocks, 256, 0, stream>>>(z1, fc2w + (size_t)l * HID * HID,
                                               fc2b + l * HID, Hl[l], bnscale, bnshift, 1,
                                               stats, N_NODES);
        bn_finalize<<<1, 128, 0, stream>>>(stats, bng + l * HID, bnb + l * HID, invN,
                                           bnscale, bnshift);
        bn_apply<<<elemBlocks, 256, 0, stream>>>(Hl[l], Hl[l], bnscale, bnshift, N_NODES, 1);
        xin = Hl[l];
    }

    // JK attention -> x0 (reused)
    jk_attn<<<(int)(((long)N_NODES * 64 + 255) / 256), 256, 0, stream>>>(
        Hl[0], Hl[1], Hl[2], Hl[3], att, x0);

    // pooling
    hipMemsetAsync(gstart, 0, 2 * N_GRAPHS * sizeof(int), stream);
    graph_ranges<<<nodeBlocks, 256, 0, stream>>>(batch, gstart, gend);
    pool_kernel<<<N_GRAPHS, 128, 0, stream>>>(x0, gstart, gend, pw, pooled);

    // head
    head_kernel<<<N_GRAPHS, 128, 0, stream>>>(pooled, fcAw, fcAb, lng, lnb, fcBw, fcBb, out);
}

// Round 3
// 944.065 us; speedup vs baseline: 5.5757x; 1.5661x over previous
//
#include <hip/hip_runtime.h>
#include <math.h>

#define N_NODES 50000
#define N_EDGES 600000
#define N_GRAPHS 512
#define HID 128
#define LAT 64
#define NL 4
#define LDA 136  // padded LDS row stride (bf16 elems): +16B breaks b128 bank aliasing

typedef __attribute__((ext_vector_type(8))) __bf16 bf16x8;
typedef __attribute__((ext_vector_type(4))) float f32x4;

union Chunk {
    bf16x8 v;
    uint4 u4;
    ushort us[8];
};

__device__ __forceinline__ float gelu_exact(float x) {
    return 0.5f * x * (1.0f + erff(x * 0.70710678118654752f));
}
__device__ __forceinline__ float bf2f(ushort h) {
    return __uint_as_float(((unsigned int)h) << 16);
}
__device__ __forceinline__ ushort f2bf(float f) {  // RNE
    unsigned int u = __float_as_uint(f);
    unsigned int r = (u + 0x7FFFu + ((u >> 16) & 1u)) >> 16;
    return (ushort)r;
}

// ---------------------------------------------------------------------------
// Weight pre-transpose + bf16 convert: Wt[g][n][k] = W_g[k][n], g=0..3 fc1, 4..7 fc2
// ---------------------------------------------------------------------------
__global__ __launch_bounds__(256) void wt_build(const float* __restrict__ fc1w,
                                                const float* __restrict__ fc2w,
                                                ushort* __restrict__ Wt) {
    int i = blockIdx.x * 256 + threadIdx.x;  // 8*16384 = 131072
    if (i >= 8 * HID * HID) return;
    int g = i >> 14;
    int rem = i & 16383;
    int n = rem >> 7, k = rem & 127;
    const float* W = (g < 4) ? (fc1w + (long)g * HID * HID) : (fc2w + (long)(g - 4) * HID * HID);
    Wt[i] = f2bf(W[k * HID + n]);
}

// ---------------------------------------------------------------------------
// Column stats (sum, sumsq) over M x 128 fp32 matrix
// ---------------------------------------------------------------------------
__global__ __launch_bounds__(256) void col_stats(const float* __restrict__ X, int M,
                                                 float* __restrict__ stats) {
    __shared__ float sh[2][8][HID];
    int t = threadIdx.x;
    int tx = t & 31, ty = t >> 5;
    int r0 = blockIdx.x * 64;
    float s[4] = {0, 0, 0, 0}, q[4] = {0, 0, 0, 0};
    for (int i = 0; i < 8; ++i) {
        int r = r0 + ty + 8 * i;
        if (r < M) {
            float4 v = *(const float4*)(X + (long)r * HID + 4 * tx);
            s[0] += v.x; s[1] += v.y; s[2] += v.z; s[3] += v.w;
            q[0] += v.x * v.x; q[1] += v.y * v.y; q[2] += v.z * v.z; q[3] += v.w * v.w;
        }
    }
    for (int c = 0; c < 4; ++c) { sh[0][ty][4 * tx + c] = s[c]; sh[1][ty][4 * tx + c] = q[c]; }
    __syncthreads();
    if (ty == 0) {
        for (int c = 0; c < 4; ++c) {
            float a = 0, b = 0;
            for (int j = 0; j < 8; ++j) { a += sh[0][j][4 * tx + c]; b += sh[1][j][4 * tx + c]; }
            atomicAdd(stats + 4 * tx + c, a);
            atomicAdd(stats + HID + 4 * tx + c, b);
        }
    }
}

// scale = g*rsqrt(var+eps); shift = b - mean*scale. Also zeroes stats for next user.
__global__ void bn_finalize(float* __restrict__ stats, const float* __restrict__ g,
                            const float* __restrict__ b, float invN,
                            float* __restrict__ scale, float* __restrict__ shift) {
    int c = threadIdx.x;
    float mean = stats[c] * invN;
    float var = stats[HID + c] * invN - mean * mean;
    float sc = g[c] * rsqrtf(var + 1e-5f);
    scale[c] = sc;
    shift[c] = b[c] - mean * sc;
    stats[c] = 0.f;
    stats[HID + c] = 0.f;
}

// Ybf = bf16(maybe_gelu(X*scale + shift)), X fp32
__global__ __launch_bounds__(256) void bn_apply2(const float* __restrict__ X,
                                                 ushort* __restrict__ Ybf,
                                                 const float* __restrict__ scale,
                                                 const float* __restrict__ shift,
                                                 int doGelu) {
    int i = blockIdx.x * blockDim.x + threadIdx.x;
    if (i >= N_NODES * (HID / 4)) return;
    int c4 = (i & 31) * 4;
    float4 v = ((const float4*)X)[i];
    float4 sc = *(const float4*)(scale + c4);
    float4 sf = *(const float4*)(shift + c4);
    v.x = v.x * sc.x + sf.x;
    v.y = v.y * sc.y + sf.y;
    v.z = v.z * sc.z + sf.z;
    v.w = v.w * sc.w + sf.w;
    if (doGelu) {
        v.x = gelu_exact(v.x); v.y = gelu_exact(v.y);
        v.z = gelu_exact(v.z); v.w = gelu_exact(v.w);
    }
    ushort4 w;
    w.x = f2bf(v.x); w.y = f2bf(v.y); w.z = f2bf(v.z); w.w = f2bf(v.w);
    ((ushort4*)Ybf)[i] = w;
}

// ---------------------------------------------------------------------------
// CSR build: counting sort of edges by dst
// ---------------------------------------------------------------------------
__global__ __launch_bounds__(256) void csr_count(const int* __restrict__ dst,
                                                 int* __restrict__ counts) {
    int e = blockIdx.x * blockDim.x + threadIdx.x;
    if (e >= N_EDGES) return;
    atomicAdd(counts + dst[e], 1);
}

__global__ __launch_bounds__(256) void scan_pass1(const int* __restrict__ counts,
                                                  int* __restrict__ offs,
                                                  int* __restrict__ bsum) {
    __shared__ int sh[256];
    int t = threadIdx.x;
    int i = blockIdx.x * 256 + t;
    int v = (i < N_NODES) ? counts[i] : 0;
    sh[t] = v;
    __syncthreads();
    for (int off = 1; off < 256; off <<= 1) {
        int a = (t >= off) ? sh[t - off] : 0;
        __syncthreads();
        sh[t] += a;
        __syncthreads();
    }
    if (i < N_NODES) offs[i] = sh[t] - v;
    if (t == 255) bsum[blockIdx.x] = sh[255];
}

__global__ __launch_bounds__(256) void scan_pass2(int* __restrict__ bsum, int nblk) {
    __shared__ int sh[256];
    int t = threadIdx.x;
    int v = (t < nblk) ? bsum[t] : 0;
    sh[t] = v;
    __syncthreads();
    for (int off = 1; off < 256; off <<= 1) {
        int a = (t >= off) ? sh[t - off] : 0;
        __syncthreads();
        sh[t] += a;
        __syncthreads();
    }
    if (t < nblk) bsum[t] = sh[t] - v;
}

__global__ __launch_bounds__(256) void scan_pass3(int* __restrict__ offs,
                                                  const int* __restrict__ bsum,
                                                  int* __restrict__ cursor) {
    int i = blockIdx.x * 256 + threadIdx.x;
    if (i >= N_NODES) return;
    int o = offs[i] + bsum[blockIdx.x];
    offs[i] = o;
    cursor[i] = o;
}

__global__ __launch_bounds__(256) void csr_fill(const int* __restrict__ src,
                                                const int* __restrict__ dst,
                                                int* __restrict__ cursor,
                                                int* __restrict__ csr) {
    int e = blockIdx.x * blockDim.x + threadIdx.x;
    if (e >= N_EDGES) return;
    int pos = atomicAdd(cursor + dst[e], 1);
    csr[pos] = src[e];
}

// ---------------------------------------------------------------------------
// GIN aggregation (bf16 in/out, fp32 accumulate): Hp[n] = (1+eps)*X[n] + sum X[nbr]
// 32 lanes per node (4 cols each), 8 nodes per 256-block
// ---------------------------------------------------------------------------
__global__ __launch_bounds__(256) void gin_gather_bf(const ushort* __restrict__ Xbf,
                                                     ushort* __restrict__ Hp,
                                                     const int* __restrict__ offs,
                                                     const int* __restrict__ counts,
                                                     const int* __restrict__ csr,
                                                     const float* __restrict__ eps, int l) {
    int t = threadIdx.x;
    int tx = t & 31;
    int node = blockIdx.x * 8 + (t >> 5);
    if (node >= N_NODES) return;
    float ev = 1.0f + eps[l];
    ushort4 sv = *(const ushort4*)(Xbf + (long)node * HID + 4 * tx);
    float a0 = bf2f(sv.x) * ev, a1 = bf2f(sv.y) * ev, a2 = bf2f(sv.z) * ev, a3 = bf2f(sv.w) * ev;
    int o = offs[node];
    int d = counts[node];
    for (int k = 0; k < d; ++k) {
        int s = csr[o + k];
        ushort4 v = *(const ushort4*)(Xbf + (long)s * HID + 4 * tx);
        a0 += bf2f(v.x); a1 += bf2f(v.y); a2 += bf2f(v.z); a3 += bf2f(v.w);
    }
    ushort4 w;
    w.x = f2bf(a0); w.y = f2bf(a1); w.z = f2bf(a2); w.w = f2bf(a3);
    *(ushort4*)(Hp + (long)node * HID + 4 * tx) = w;
}

// ---------------------------------------------------------------------------
// MFMA GEMM: C[M,128] = A'[M,128] @ W[128,128] + bias, where A' = A (applyIn=0)
// or A' = gelu(A*scale+shift) (applyIn=1). A is bf16. Wt is bf16 pretransposed
// [n][k]. Output: Cf fp32 OR Cbf bf16. Column sum/sumsq accumulated into stats.
// Block = 256 thr = 4 waves, 64 rows; wave w: rows 16w..16w+15, cols 0..127.
// ---------------------------------------------------------------------------
__global__ __launch_bounds__(256) void gemm_mfma(const ushort* __restrict__ Abf,
                                                 const ushort* __restrict__ Wt,
                                                 const float* __restrict__ bias,
                                                 float* __restrict__ Cf,
                                                 ushort* __restrict__ Cbf,
                                                 const float* __restrict__ scale,
                                                 const float* __restrict__ shift,
                                                 int applyIn, float* __restrict__ stats,
                                                 int M) {
    __shared__ __align__(16) ushort As[64 * LDA];   // 17408 B
    __shared__ __align__(16) ushort Bs[128 * LDA];  // 34816 B
    int t = threadIdx.x;
    int r0 = blockIdx.x * 64;

    // stage Wt -> Bs (2048 16B chunks)
#pragma unroll
    for (int it = 0; it < 8; ++it) {
        int c = it * 256 + t;
        int n = c >> 4, ko = (c & 15) * 8;
        *(uint4*)(Bs + n * LDA + ko) = *(const uint4*)(Wt + n * HID + ko);
    }
    // stage A -> As (1024 16B chunks), optional BN+gelu in bf16->fp32->bf16
#pragma unroll
    for (int it = 0; it < 4; ++it) {
        int c = it * 256 + t;
        int row = c >> 4, ko = (c & 15) * 8;
        int r = r0 + row;
        Chunk ch;
        ch.u4 = make_uint4(0, 0, 0, 0);
        if (r < M) ch.u4 = *(const uint4*)(Abf + (long)r * HID + ko);
        if (applyIn) {
#pragma unroll
            for (int j = 0; j < 8; ++j) {
                float f = bf2f(ch.us[j]);
                f = f * scale[ko + j] + shift[ko + j];
                ch.us[j] = f2bf(gelu_exact(f));
            }
        }
        *(uint4*)(As + row * LDA + ko) = ch.u4;
    }
    __syncthreads();

    int lane = t & 63, w = t >> 6;
    int m = lane & 15, q = lane >> 4;  // A-row / B-col = m; k-octet = q
    const ushort* a_base = As + (w * 16 + m) * LDA + q * 8;
    const ushort* b_base = Bs + m * LDA + q * 8;

    f32x4 acc[8];
#pragma unroll
    for (int nt = 0; nt < 8; ++nt) acc[nt] = (f32x4){0.f, 0.f, 0.f, 0.f};

#pragma unroll
    for (int kc = 0; kc < 4; ++kc) {
        bf16x8 a = *(const bf16x8*)(a_base + kc * 32);
#pragma unroll
        for (int nt = 0; nt < 8; ++nt) {
            bf16x8 b = *(const bf16x8*)(b_base + nt * 16 * LDA + kc * 32);
            acc[nt] = __builtin_amdgcn_mfma_f32_16x16x32_bf16(a, b, acc[nt], 0, 0, 0);
        }
    }

    // epilogue: bias, store, per-column sum/sumsq
    float s_arr[8], q_arr[8];
    int rbase = r0 + w * 16 + q * 4;
#pragma unroll
    for (int nt = 0; nt < 8; ++nt) {
        int col = nt * 16 + m;
        float bb = bias[col];
        float s = 0.f, ss = 0.f;
#pragma unroll
        for (int r = 0; r < 4; ++r) {
            int row = rbase + r;
            if (row < M) {
                float z = acc[nt][r] + bb;
                long idx = (long)row * HID + col;
                if (Cf) Cf[idx] = z;
                else Cbf[idx] = f2bf(z);
                s += z;
                ss += z * z;
            }
        }
        s += __shfl_xor(s, 16); s += __shfl_xor(s, 32);
        ss += __shfl_xor(ss, 16); ss += __shfl_xor(ss, 32);
        s_arr[nt] = s;
        q_arr[nt] = ss;
    }
    __syncthreads();  // done reading As/Bs; reuse As as fp32 scratch
    float* shs = (float*)As;  // [2][4 waves][128 cols] = 4 KB
    if (q == 0) {
#pragma unroll
        for (int nt = 0; nt < 8; ++nt) {
            shs[w * HID + nt * 16 + m] = s_arr[nt];
            shs[512 + w * HID + nt * 16 + m] = q_arr[nt];
        }
    }
    __syncthreads();
    if (t < HID) {
        float a = 0, b = 0;
#pragma unroll
        for (int j = 0; j < 4; ++j) {
            a += shs[j * HID + t];
            b += shs[512 + j * HID + t];
        }
        atomicAdd(stats + t, a);
        atomicAdd(stats + HID + t, b);
    }
}

// JK attention over 4 layers (bf16 inputs, fp32 out): one wave per node
__global__ __launch_bounds__(256) void jk_attn_bf(const ushort* __restrict__ H0,
                                                  const ushort* __restrict__ H1,
                                                  const ushort* __restrict__ H2,
                                                  const ushort* __restrict__ H3,
                                                  const float* __restrict__ att,
                                                  float* __restrict__ Y) {
    long gid = (long)blockIdx.x * blockDim.x + threadIdx.x;
    int lane = (int)(gid & 63);
    int node = (int)(gid >> 6);
    if (node >= N_NODES) return;
    const ushort* Hs[4] = {H0, H1, H2, H3};
    float hx[4], hy[4], sc[4];
#pragma unroll
    for (int l = 0; l < 4; ++l) {
        unsigned int u = *(const unsigned int*)(Hs[l] + (long)node * HID + 2 * lane);
        float vx = bf2f((ushort)(u & 0xFFFF));
        float vy = bf2f((ushort)(u >> 16));
        float2 a = *(const float2*)(att + l * HID + 2 * lane);
        hx[l] = vx; hy[l] = vy;
        float p = vx * a.x + vy * a.y;
#pragma unroll
        for (int off = 32; off > 0; off >>= 1) p += __shfl_xor(p, off);
        sc[l] = p * (1.0f / HID);
    }
    float mm = fmaxf(fmaxf(sc[0], sc[1]), fmaxf(sc[2], sc[3]));
    float e[4], se = 0.f;
#pragma unroll
    for (int l = 0; l < 4; ++l) { e[l] = expf(sc[l] - mm); se += e[l]; }
    float inv = 1.0f / se;
    float ox = 0.f, oy = 0.f;
#pragma unroll
    for (int l = 0; l < 4; ++l) {
        float a = e[l] * inv;
        ox += a * hx[l];
        oy += a * hy[l];
    }
    float2 o = make_float2(ox, oy);
    *(float2*)(Y + (long)node * HID + 2 * lane) = o;
}

__global__ void graph_ranges(const int* __restrict__ batch, int* __restrict__ gstart,
                             int* __restrict__ gend) {
    int n = blockIdx.x * blockDim.x + threadIdx.x;
    if (n >= N_NODES) return;
    int b = batch[n];
    if (n == 0 || batch[n - 1] != b) gstart[b] = n;
    if (n == N_NODES - 1 || batch[n + 1] != b) gend[b] = n + 1;
}

__global__ __launch_bounds__(128) void pool_kernel(const float* __restrict__ X,
                                                   const int* __restrict__ gstart,
                                                   const int* __restrict__ gend,
                                                   const float* __restrict__ pw,
                                                   float* __restrict__ pooled) {
    int g = blockIdx.x;
    int f = threadIdx.x;
    float w0 = pw[0], w1 = pw[1], w2 = pw[2];
    float m = fmaxf(w0, fmaxf(w1, w2));
    float e0 = expf(w0 - m), e1 = expf(w1 - m), e2 = expf(w2 - m);
    float inv = 1.0f / (e0 + e1 + e2);
    e0 *= inv; e1 *= inv; e2 *= inv;
    int s = gstart[g], e = gend[g];
    float sum = 0.f, mx = -INFINITY;
    for (int n = s; n < e; ++n) {
        float v = X[(long)n * HID + f];
        sum += v;
        mx = fmaxf(mx, v);
    }
    int cnt = e - s;
    float mean = cnt > 0 ? sum / (float)cnt : 0.f;
    float mxv = cnt > 0 ? mx : 0.f;
    pooled[g * HID + f] = sum * e0 + mean * e1 + mxv * e2;
}

__global__ __launch_bounds__(128) void head_kernel(const float* __restrict__ pooled,
                                                   const float* __restrict__ fcAw,
                                                   const float* __restrict__ fcAb,
                                                   const float* __restrict__ lng,
                                                   const float* __restrict__ lnb,
                                                   const float* __restrict__ fcBw,
                                                   const float* __restrict__ fcBb,
                                                   float* __restrict__ out) {
    __shared__ float p[HID], q[HID], red[HID];
    int g = blockIdx.x, j = threadIdx.x;
    p[j] = pooled[g * HID + j];
    __syncthreads();
    float acc = fcAb[j];
    for (int k = 0; k < HID; ++k) acc += p[k] * fcAw[k * HID + j];
    red[j] = acc;
    __syncthreads();
    for (int off = 64; off > 0; off >>= 1) {
        if (j < off) red[j] += red[j + off];
        __syncthreads();
    }
    float mean = red[0] * (1.0f / HID);
    __syncthreads();
    float d = acc - mean;
    red[j] = d * d;
    __syncthreads();
    for (int off = 64; off > 0; off >>= 1) {
        if (j < off) red[j] += red[j + off];
        __syncthreads();
    }
    float var = red[0] * (1.0f / HID);
    float y = d * rsqrtf(var + 1e-5f) * lng[j] + lnb[j];
    q[j] = gelu_exact(y) + p[j];
    __syncthreads();
    if (j < LAT) {
        float o = fcBb[j];
        for (int k = 0; k < HID; ++k) o += q[k] * fcBw[k * LAT + j];
        out[g * LAT + j] = o;
    }
}

extern "C" void kernel_launch(void* const* d_in, const int* in_sizes, int n_in,
                              void* d_out, int out_size, void* d_ws, size_t ws_size,
                              hipStream_t stream) {
    const float* x = (const float*)d_in[0];
    const int* ei = (const int*)d_in[1];
    const int* src = ei;
    const int* dst = ei + N_EDGES;
    const int* batch = (const int*)d_in[2];
    const float* ibn_g = (const float*)d_in[3];
    const float* ibn_b = (const float*)d_in[4];
    const float* eps = (const float*)d_in[5];
    const float* fc1w = (const float*)d_in[6];
    const float* fc1b = (const float*)d_in[7];
    const float* bn1g = (const float*)d_in[8];
    const float* bn1b = (const float*)d_in[9];
    const float* fc2w = (const float*)d_in[10];
    const float* fc2b = (const float*)d_in[11];
    const float* bng = (const float*)d_in[12];
    const float* bnb = (const float*)d_in[13];
    const float* att = (const float*)d_in[14];
    const float* pw = (const float*)d_in[15];
    const float* fcAw = (const float*)d_in[16];
    const float* fcAb = (const float*)d_in[17];
    const float* lng = (const float*)d_in[18];
    const float* lnb = (const float*)d_in[19];
    const float* fcBw = (const float*)d_in[20];
    const float* fcBb = (const float*)d_in[21];
    float* out = (float*)d_out;

    const size_t NH = (size_t)N_NODES * HID;
    char* w8 = (char*)d_ws;
    ushort* x0bf = (ushort*)w8;            w8 += NH * 2;
    ushort* hprebf = (ushort*)w8;          w8 += NH * 2;
    ushort* z1bf = (ushort*)w8;            w8 += NH * 2;
    ushort* Hlbf[NL];
    for (int l = 0; l < NL; ++l) { Hlbf[l] = (ushort*)w8; w8 += NH * 2; }
    float* ztmp = (float*)w8;              w8 += NH * 4;
    float* stats = (float*)w8;             w8 += 256 * 4;
    float* bnscale = (float*)w8;           w8 += HID * 4;
    float* bnshift = (float*)w8;           w8 += HID * 4;
    float* pooled = (float*)w8;            w8 += (size_t)N_GRAPHS * HID * 4;
    int* gstart = (int*)w8;                w8 += N_GRAPHS * 4;
    int* gend = (int*)w8;                  w8 += N_GRAPHS * 4;
    int* counts = (int*)w8;                w8 += N_NODES * 4;
    int* offs = (int*)w8;                  w8 += N_NODES * 4;
    int* cursor = (int*)w8;                w8 += N_NODES * 4;
    int* bsum = (int*)w8;                  w8 += 256 * 4;
    int* csr = (int*)w8;                   w8 += (size_t)N_EDGES * 4;
    ushort* WtBf = (ushort*)w8;            w8 += (size_t)8 * HID * HID * 2;

    const int elemBlocks = (N_NODES * (HID / 4) + 255) / 256;  // 6250
    const int rowBlocks = (N_NODES + 63) / 64;                 // 782
    const int nodeBlocks = (N_NODES + 255) / 256;              // 196
    const int edgeBlocks = (N_EDGES + 255) / 256;              // 2344
    const float invN = 1.0f / (float)N_NODES;

    // weights: transpose + bf16 once
    wt_build<<<512, 256, 0, stream>>>(fc1w, fc2w, WtBf);

    // CSR build (counting sort by dst)
    hipMemsetAsync(counts, 0, N_NODES * sizeof(int), stream);
    csr_count<<<edgeBlocks, 256, 0, stream>>>(dst, counts);
    scan_pass1<<<nodeBlocks, 256, 0, stream>>>(counts, offs, bsum);
    scan_pass2<<<1, 256, 0, stream>>>(bsum, nodeBlocks);
    scan_pass3<<<nodeBlocks, 256, 0, stream>>>(offs, bsum, cursor);
    csr_fill<<<edgeBlocks, 256, 0, stream>>>(src, dst, cursor, csr);

    // input BatchNorm -> bf16 x0
    hipMemsetAsync(stats, 0, 256 * sizeof(float), stream);
    col_stats<<<rowBlocks, 256, 0, stream>>>(x, N_NODES, stats);
    bn_finalize<<<1, 128, 0, stream>>>(stats, ibn_g, ibn_b, invN, bnscale, bnshift);
    bn_apply2<<<elemBlocks, 256, 0, stream>>>(x, x0bf, bnscale, bnshift, 0);

    const ushort* xin = x0bf;
    for (int l = 0; l < NL; ++l) {
        gin_gather_bf<<<(N_NODES + 7) / 8, 256, 0, stream>>>(xin, hprebf, offs, counts,
                                                             csr, eps, l);
        // z1 = hpre @ fc1 + b1 (bf16 out), stats -> bn1
        gemm_mfma<<<rowBlocks, 256, 0, stream>>>(hprebf, WtBf + (size_t)l * HID * HID,
                                                 fc1b + l * HID, nullptr, z1bf, nullptr,
                                                 nullptr, 0, stats, N_NODES);
        bn_finalize<<<1, 128, 0, stream>>>(stats, bn1g + l * HID, bn1b + l * HID, invN,
                                           bnscale, bnshift);
        // ztmp = gelu(bn1(z1)) @ fc2 + b2 (fp32 out), stats -> bn
        gemm_mfma<<<rowBlocks, 256, 0, stream>>>(z1bf, WtBf + (size_t)(4 + l) * HID * HID,
                                                 fc2b + l * HID, ztmp, nullptr, bnscale,
                                                 bnshift, 1, stats, N_NODES);
        bn_finalize<<<1, 128, 0, stream>>>(stats, bng + l * HID, bnb + l * HID, invN,
                                           bnscale, bnshift);
        bn_apply2<<<elemBlocks, 256, 0, stream>>>(ztmp, Hlbf[l], bnscale, bnshift, 1);
        xin = Hlbf[l];
    }

    // JK attention -> ztmp (fp32)
    jk_attn_bf<<<(int)(((long)N_NODES * 64 + 255) / 256), 256, 0, stream>>>(
        Hlbf[0], Hlbf[1], Hlbf[2], Hlbf[3], att, ztmp);

    // pooling
    hipMemsetAsync(gstart, 0, 2 * N_GRAPHS * sizeof(int), stream);
    graph_ranges<<<nodeBlocks, 256, 0, stream>>>(batch, gstart, gend);
    pool_kernel<<<N_GRAPHS, 128, 0, stream>>>(ztmp, gstart, gend, pw, pooled);

    // head
    head_kernel<<<N_GRAPHS, 128, 0, stream>>>(pooled, fcAw, fcAb, lng, lnb, fcBw, fcBb, out);
}